// Round 13
// baseline (346.476 us; speedup 1.0000x reference)
//
#include <hip/hip_runtime.h>

// db2 filters, pre-flipped (cross-correlation form used by ptwt)
#define F_LO0 0.4829629131445341f
#define F_LO1 0.8365163037378079f
#define F_LO2 0.22414386804185735f
#define F_LO3 (-0.12940952255092145f)
#define F_HI0 (-0.12940952255092145f)
#define F_HI1 (-0.22414386804185735f)
#define F_HI2 0.8365163037378079f
#define F_HI3 (-0.4829629131445341f)

__device__ __forceinline__ int reflect_idx(int r, int n) {
    r = (r < 0) ? -r : r;
    r = (r >= n) ? 2 * n - 2 - r : r;
    return r;
}

// Raw barrier: LDS drain only. __syncthreads() would also drain vmcnt(0),
// killing the cross-tile register prefetch that this kernel relies on.
#define BARRIER()                                              \
    do {                                                       \
        asm volatile("s_waitcnt lgkmcnt(0)" ::: "memory");     \
        __builtin_amdgcn_s_barrier();                          \
    } while (0)

// vertical 4-tap filter on float4 lanes (4 columns at once)
__device__ __forceinline__ float4 vfilt(const float4 a, const float4 b,
                                        const float4 c, const float4 d,
                                        float c0, float c1, float c2, float c3) {
    return make_float4(c0 * a.x + c1 * b.x + c2 * c.x + c3 * d.x,
                       c0 * a.y + c1 * b.y + c2 * c.y + c3 * d.y,
                       c0 * a.z + c1 * b.z + c2 * c.z + c3 * d.z,
                       c0 * a.w + c1 * b.w + c2 * c.w + c3 * d.w);
}

// Persistent-block fused 3-level WPT + weighted squared-sum.
// 512 blocks x ~30 tiles. Per tile: h1 (from prefetched regs) -> v1 -> [patch]
// -> wave-autonomous L2/L3 (R10 bodies verbatim). Next tile's 10 float4 global
// loads are issued right after the current tile's are consumed and stay in
// flight across the raw barriers, hidden under ~6us of compute.
__global__ void __launch_bounds__(512) k_wpt_persist(
    const float* __restrict__ p, const float* __restrict__ t,
    float* __restrict__ partial) {
    constexpr int N0 = 512, N1 = 257, N2 = 130, N3 = 66;

    __shared__ __align__(16) float sA[6080];  // L1 bands 4 x 38 rows x stride 40
    __shared__ __align__(16) float sB[6912];  // h1 out lo/hi 78x40 -> 8 wave scratches [4][12][18]
    __shared__ float wsum[8];

    const int b = blockIdx.x;                       // 512 blocks
    const int g0 = b * 30 + ((b < 192) ? b : 192);  // 15552 = 192*31 + 320*30
    const int cnt = 30 + ((b < 192) ? 1 : 0);

    const int tid = threadIdx.x;
    const int hr = tid / 5, hk = tid - (tid / 5) * 5;  // h1 item (tid<390)

    float4 P[5], T[5];  // in-flight prefetch for the NEXT tile

    auto prefetch = [&](int g) {
        int img = g / 81;
        int tt = g - img * 81;
        int TAn = (tt / 9) * 8;
        int TBn = (tt - (tt / 9) * 9) * 8;
        int O0rn = 8 * TAn - 14, O0cn = 8 * TBn - 16;
        int grr = reflect_idx(O0rn + hr, N0);
        const float* __restrict__ prow = p + (size_t)img * (N0 * N0) + (size_t)grr * N0;
        const float* __restrict__ trow = t + (size_t)img * (N0 * N0) + (size_t)grr * N0;
        int gc0 = O0cn + 16 * hk;
        if ((unsigned)gc0 <= 492u) {
#pragma unroll
            for (int q = 0; q < 5; ++q) {
                P[q] = *(const float4*)(prow + gc0 + 4 * q);
                T[q] = *(const float4*)(trow + gc0 + 4 * q);
            }
        } else {
#pragma unroll
            for (int q = 0; q < 5; ++q) {
                int c0 = reflect_idx(gc0 + 4 * q + 0, N0);
                int c1 = reflect_idx(gc0 + 4 * q + 1, N0);
                int c2 = reflect_idx(gc0 + 4 * q + 2, N0);
                int c3 = reflect_idx(gc0 + 4 * q + 3, N0);
                P[q] = make_float4(prow[c0], prow[c1], prow[c2], prow[c3]);
                T[q] = make_float4(trow[c0], trow[c1], trow[c2], trow[c3]);
            }
        }
    };

    // prologue: issue loads for the first tile
    if (tid < 390) prefetch(g0);

    float local = 0.f;
    const int w = tid >> 6;
    const int ln = tid & 63;
    const int bnd = w >> 1;     // level-1 band 0..3
    const int hf = w & 1;       // row half
    const int off = hf * 6;     // L2 tile rows off..off+11
    float* scr = sB + w * 864;  // private [4][12][18]

    for (int it = 0; it < cnt; ++it) {
        const int g = g0 + it;
        const int img = g / 81;
        const int tt = g - img * 81;
        const int TA = (tt / 9) * 8;
        const int TB = (tt - (tt / 9) * 9) * 8;
        const int O1r = 4 * TA - 6, O1c = 4 * TB - 6;
        const int O2r = 2 * TA - 2, O2c = 2 * TB - 2;
        const bool edge = (TA == 0) || (TA == 64) || (TB == 0) || (TB == 64);

        // ---- h1: consume prefetched regs, then issue next tile's loads ----
        if (tid < 390) {
            float v[20];
#pragma unroll
            for (int q = 0; q < 5; ++q) {
                v[4 * q + 0] = P[q].x - T[q].x;
                v[4 * q + 1] = P[q].y - T[q].y;
                v[4 * q + 2] = P[q].z - T[q].z;
                v[4 * q + 3] = P[q].w - T[q].w;
            }
            if (it + 1 < cnt) prefetch(g + 1);  // in flight across barriers below
            float* dst = sB + hr * 40 + 8 * hk;
            *(float4*)(dst) = make_float4(
                F_LO0 * v[2] + F_LO1 * v[3] + F_LO2 * v[4] + F_LO3 * v[5],
                F_LO0 * v[4] + F_LO1 * v[5] + F_LO2 * v[6] + F_LO3 * v[7],
                F_LO0 * v[6] + F_LO1 * v[7] + F_LO2 * v[8] + F_LO3 * v[9],
                F_LO0 * v[8] + F_LO1 * v[9] + F_LO2 * v[10] + F_LO3 * v[11]);
            *(float4*)(dst + 4) = make_float4(
                F_LO0 * v[10] + F_LO1 * v[11] + F_LO2 * v[12] + F_LO3 * v[13],
                F_LO0 * v[12] + F_LO1 * v[13] + F_LO2 * v[14] + F_LO3 * v[15],
                F_LO0 * v[14] + F_LO1 * v[15] + F_LO2 * v[16] + F_LO3 * v[17],
                F_LO0 * v[16] + F_LO1 * v[17] + F_LO2 * v[18] + F_LO3 * v[19]);
            *(float4*)(dst + 3120) = make_float4(
                F_HI0 * v[2] + F_HI1 * v[3] + F_HI2 * v[4] + F_HI3 * v[5],
                F_HI0 * v[4] + F_HI1 * v[5] + F_HI2 * v[6] + F_HI3 * v[7],
                F_HI0 * v[6] + F_HI1 * v[7] + F_HI2 * v[8] + F_HI3 * v[9],
                F_HI0 * v[8] + F_HI1 * v[9] + F_HI2 * v[10] + F_HI3 * v[11]);
            *(float4*)(dst + 3124) = make_float4(
                F_HI0 * v[10] + F_HI1 * v[11] + F_HI2 * v[12] + F_HI3 * v[13],
                F_HI0 * v[12] + F_HI1 * v[13] + F_HI2 * v[14] + F_HI3 * v[15],
                F_HI0 * v[14] + F_HI1 * v[15] + F_HI2 * v[16] + F_HI3 * v[17],
                F_HI0 * v[16] + F_HI1 * v[17] + F_HI2 * v[18] + F_HI3 * v[19]);
        }
        BARRIER();

        // ---- v1: 38 rows x 10 groups -> sA L1 bands (stride 40) ----
        if (tid < 380) {
            int r1 = tid / 10, k = tid - (tid / 10) * 10;
            const float* blo = sB + (2 * r1) * 40 + 4 * k;
            const float* bhi = blo + 3120;
            float4 L0 = *(const float4*)(blo);
            float4 L1v = *(const float4*)(blo + 40);
            float4 L2v = *(const float4*)(blo + 80);
            float4 L3v = *(const float4*)(blo + 120);
            float4 H0 = *(const float4*)(bhi);
            float4 H1 = *(const float4*)(bhi + 40);
            float4 H2 = *(const float4*)(bhi + 80);
            float4 H3 = *(const float4*)(bhi + 120);
            float4 b0 = vfilt(L0, L1v, L2v, L3v, F_LO0, F_LO1, F_LO2, F_LO3);
            float4 b1 = vfilt(L0, L1v, L2v, L3v, F_HI0, F_HI1, F_HI2, F_HI3);
            float4 b2 = vfilt(H0, H1, H2, H3, F_LO0, F_LO1, F_LO2, F_LO3);
            float4 b3 = vfilt(H0, H1, H2, H3, F_HI0, F_HI1, F_HI2, F_HI3);
            int wo = r1 * 40 + 4 * k;
            *(float4*)(sA + wo) = b0;
            *(float4*)(sA + 1520 + wo) = b1;
            *(float4*)(sA + 3040 + wo) = b2;
            *(float4*)(sA + 4560 + wo) = b3;
        }
        BARRIER();
        if (edge) {  // patch reflected L1 slots (sources are fixed points)
#pragma unroll
            for (int pit = 0; pit < 3; ++pit) {
                int e = pit * 512 + tid;
                if (e < 1444) {
                    int lr = e / 38, lc = e - lr * 38;
                    int sr = reflect_idx(O1r + lr, N1) - O1r;
                    int sc = reflect_idx(O1c + lc, N1) - O1c;
                    if ((sr != lr || sc != lc) && (unsigned)sr < 38u && (unsigned)sc < 38u) {
                        int da = lr * 40 + lc;
                        int sa = sr * 40 + sc;
                        sA[da] = sA[sa];
                        sA[1520 + da] = sA[1520 + sa];
                        sA[3040 + da] = sA[3040 + sa];
                        sA[4560 + da] = sA[4560 + sa];
                    }
                }
            }
            BARRIER();
        }

        // ---- wave-autonomous levels 2+3 (no barriers; R10 bodies) ----
        const float* L1b = sA + bnd * 1520;
        if (ln < 54) {
            const int c = ln % 18, s = ln / 18;
#pragma unroll
            for (int tq = 0; tq < 4; ++tq) {
                const int r2l = 3 * tq + s;  // 0..11
                const float* base = L1b + (2 * (off + r2l)) * 40 + 2 * c;
                float lo[4], hi[4];
#pragma unroll
                for (int u = 0; u < 4; ++u) {
                    float2 a = *(const float2*)(base + u * 40);
                    float2 d = *(const float2*)(base + u * 40 + 2);
                    lo[u] = F_LO0 * a.x + F_LO1 * a.y + F_LO2 * d.x + F_LO3 * d.y;
                    hi[u] = F_HI0 * a.x + F_HI1 * a.y + F_HI2 * d.x + F_HI3 * d.y;
                }
                int sl = r2l * 18 + c;
                scr[sl]       = F_LO0 * lo[0] + F_LO1 * lo[1] + F_LO2 * lo[2] + F_LO3 * lo[3];
                scr[sl + 216] = F_HI0 * lo[0] + F_HI1 * lo[1] + F_HI2 * lo[2] + F_HI3 * lo[3];
                scr[sl + 432] = F_LO0 * hi[0] + F_LO1 * hi[1] + F_LO2 * hi[2] + F_LO3 * hi[3];
                scr[sl + 648] = F_HI0 * hi[0] + F_HI1 * hi[1] + F_HI2 * hi[2] + F_HI3 * hi[3];
            }
        }
        if (edge) {  // wave-local reflect patch of the private L2 scratch
#pragma unroll
            for (int q = 0; q < 4; ++q) {
                int e = q * 54 + ln;
                if (ln < 54 && e < 216) {
                    int lr = e / 18, lc = e - lr * 18;
                    int srt = reflect_idx(O2r + off + lr, N2) - O2r - off;
                    int sct = reflect_idx(O2c + lc, N2) - O2c;
                    if ((srt != lr || sct != lc) &&
                        (unsigned)srt < 12u && (unsigned)sct < 18u) {
                        int d = lr * 18 + lc, sidx = srt * 18 + sct;
#pragma unroll
                        for (int pl = 0; pl < 4; ++pl)
                            scr[d + 216 * pl] = scr[sidx + 216 * pl];
                    }
                }
            }
        }
        // h3+v3 + square + weight
        {
            const int pp = ln >> 5, rem = ln & 31, r3 = rem >> 3, j = rem & 7;
            const int i = hf * 4 + r3;
            const int sr0 = 2 * r3 + hf * 2;
            const bool valid = (TA + i < N3) && (TB + j < N3);
#pragma unroll
            for (int pi = 0; pi < 2; ++pi) {
                const int pl = 2 * pp + pi;
                const float* pb = scr + pl * 216 + sr0 * 18 + 2 * j;
                float lo[4], hi[4];
#pragma unroll
                for (int u = 0; u < 4; ++u) {
                    float2 a = *(const float2*)(pb + u * 18);
                    float2 d = *(const float2*)(pb + u * 18 + 2);
                    lo[u] = F_LO0 * a.x + F_LO1 * a.y + F_LO2 * d.x + F_LO3 * d.y;
                    hi[u] = F_HI0 * a.x + F_HI1 * a.y + F_HI2 * d.x + F_HI3 * d.y;
                }
                float o0 = F_LO0 * lo[0] + F_LO1 * lo[1] + F_LO2 * lo[2] + F_LO3 * lo[3];
                float o1 = F_HI0 * lo[0] + F_HI1 * lo[1] + F_HI2 * lo[2] + F_HI3 * lo[3];
                float o2 = F_LO0 * hi[0] + F_LO1 * hi[1] + F_LO2 * hi[2] + F_LO3 * hi[3];
                float o3 = F_HI0 * hi[0] + F_HI1 * hi[1] + F_HI2 * hi[2] + F_HI3 * hi[3];
                if (valid) {
                    float w00 = (bnd == 0 && pl == 0) ? 0.5f : 1.0f;
                    local += w00 * o0 * o0 + o1 * o1 + o2 * o2 + o3 * o3;
                }
            }
        }
        BARRIER();  // scratch/sA reads done before next tile's h1/v1 overwrite
    }

    // block reduction: 8 waves, one plain store per block
#pragma unroll
    for (int o = 32; o > 0; o >>= 1) local += __shfl_down(local, o, 64);
    if (ln == 0) wsum[w] = local;
    __syncthreads();
    if (tid == 0) {
        float ssum = 0.f;
#pragma unroll
        for (int x = 0; x < 8; ++x) ssum += wsum[x];
        partial[b] = ssum;
    }
}

// Final reduction: sum 512 per-block partials -> out[0]. Single block.
__global__ void __launch_bounds__(512) k_reduce(const float* __restrict__ part,
                                                float* __restrict__ out,
                                                float inv_den) {
    const int tid = threadIdx.x;
    float s = part[tid];
#pragma unroll
    for (int o = 32; o > 0; o >>= 1) s += __shfl_down(s, o, 64);
    __shared__ float ws_[8];
    int w = tid >> 6;
    if ((tid & 63) == 0) ws_[w] = s;
    __syncthreads();
    if (tid == 0) {
        float tot = 0.f;
#pragma unroll
        for (int i = 0; i < 8; ++i) tot += ws_[i];
        out[0] = tot * inv_den;
    }
}

extern "C" void kernel_launch(void* const* d_in, const int* in_sizes, int n_in,
                              void* d_out, int out_size, void* d_ws, size_t ws_size,
                              hipStream_t stream) {
    const float* preds = (const float*)d_in[0];
    const float* targets = (const float*)d_in[1];
    float* out = (float*)d_out;
    float* partial = (float*)d_ws;  // 512 floats

    const float inv_den = 1.0f / (192.0f * 66.0f * 66.0f);

    k_wpt_persist<<<dim3(512), dim3(512), 0, stream>>>(preds, targets, partial);
    k_reduce<<<dim3(1), dim3(512), 0, stream>>>(partial, out, inv_den);
}

// Round 14
// 202.334 us; speedup vs baseline: 1.7124x; 1.7124x over previous
//
#include <hip/hip_runtime.h>

// db2 filters, pre-flipped (cross-correlation form used by ptwt)
#define F_LO0 0.4829629131445341f
#define F_LO1 0.8365163037378079f
#define F_LO2 0.22414386804185735f
#define F_LO3 (-0.12940952255092145f)
#define F_HI0 (-0.12940952255092145f)
#define F_HI1 (-0.22414386804185735f)
#define F_HI2 0.8365163037378079f
#define F_HI3 (-0.4829629131445341f)

__device__ __forceinline__ int reflect_idx(int r, int n) {
    r = (r < 0) ? -r : r;
    r = (r >= n) ? 2 * n - 2 - r : r;
    return r;
}

// vertical 4-tap filter on float4 lanes (4 columns at once)
__device__ __forceinline__ float4 vfilt(const float4 a, const float4 b,
                                        const float4 c, const float4 d,
                                        float c0, float c1, float c2, float c3) {
    return make_float4(c0 * a.x + c1 * b.x + c2 * c.x + c3 * d.x,
                       c0 * a.y + c1 * b.y + c2 * c.y + c3 * d.y,
                       c0 * a.z + c1 * b.z + c2 * c.z + c3 * d.z,
                       c0 * a.w + c1 * b.w + c2 * c.w + c3 * d.w);
}

// Fused 3-level WPT + weighted squared-sum.
// R14: R10 front end (best measured) + instruction-lean cooperative back half:
//   L2: 324 threads, one (r2,c2) cell each -- no duplicated rows (old row-half
//       scheme recomputed 24/18 rows), 16 loads reused across 4 outputs/band,
//       write index == tid. Layout sB[16][324].
//   L3: 512 threads x 2 items, indices all shifts/masks, plane-uniform waves.
// Back half ~4.4k -> ~2.4k wave-instrs per block (~-20% of block total).
__global__ void __launch_bounds__(512) k_wpt_fused(
    const float* __restrict__ p, const float* __restrict__ t,
    float* __restrict__ partial) {
    constexpr int N0 = 512, N1 = 257, N2 = 130, N3 = 66;

    __shared__ __align__(16) float sA[6080];  // L1 bands 4 x 38 rows x stride 40
    __shared__ __align__(16) float sB[6240];  // h1 lo/hi 78x40; reused as L2 [16][324]
    __shared__ float wsum[8];

    // XCD-chunked swizzle: 15552 = 8 * 1944 (bijective)
    int bid = blockIdx.x;
    int swz = (bid & 7) * (int)(gridDim.x >> 3) + (bid >> 3);
    int img = swz / 81;
    int tt = swz - img * 81;
    int TA = (tt / 9) * 8;
    int TB = (tt % 9) * 8;

    const int tid = threadIdx.x;
    const size_t ibase = (size_t)img * (N0 * N0);

    const int O0r = 8 * TA - 14, O0c = 8 * TB - 16;  // col origin 16B-aligned
    const int O1r = 4 * TA - 6, O1c = 4 * TB - 6;
    const int O2r = 2 * TA - 2, O2c = 2 * TB - 2;
    const bool edge = (TA == 0) || (TA == 64) || (TB == 0) || (TB == 64);

    // ---- h1 from global (R10 verbatim): 390 threads = (row r 0..77, k 0..4) ----
    if (tid < 390) {
        unsigned ru = (unsigned)tid / 5u;
        const int r = (int)ru;
        const int k = tid - (int)(5u * ru);
        const int grr = reflect_idx(O0r + r, N0);
        const float* __restrict__ prow = p + ibase + (size_t)grr * N0;
        const float* __restrict__ trow = t + ibase + (size_t)grr * N0;
        const int gc0 = O0c + 16 * k;
        float v[20];
        if ((unsigned)gc0 <= 492u) {
#pragma unroll
            for (int q = 0; q < 5; ++q) {
                const float4 pv = *(const float4*)(prow + gc0 + 4 * q);
                const float4 tv = *(const float4*)(trow + gc0 + 4 * q);
                v[4 * q + 0] = pv.x - tv.x;
                v[4 * q + 1] = pv.y - tv.y;
                v[4 * q + 2] = pv.z - tv.z;
                v[4 * q + 3] = pv.w - tv.w;
            }
        } else {
#pragma unroll
            for (int x = 0; x < 20; ++x) {
                int gc = reflect_idx(gc0 + x, N0);
                v[x] = prow[gc] - trow[gc];
            }
        }
        float* dst = sB + r * 40 + 8 * k;
        *(float4*)(dst) = make_float4(
            F_LO0 * v[2] + F_LO1 * v[3] + F_LO2 * v[4] + F_LO3 * v[5],
            F_LO0 * v[4] + F_LO1 * v[5] + F_LO2 * v[6] + F_LO3 * v[7],
            F_LO0 * v[6] + F_LO1 * v[7] + F_LO2 * v[8] + F_LO3 * v[9],
            F_LO0 * v[8] + F_LO1 * v[9] + F_LO2 * v[10] + F_LO3 * v[11]);
        *(float4*)(dst + 4) = make_float4(
            F_LO0 * v[10] + F_LO1 * v[11] + F_LO2 * v[12] + F_LO3 * v[13],
            F_LO0 * v[12] + F_LO1 * v[13] + F_LO2 * v[14] + F_LO3 * v[15],
            F_LO0 * v[14] + F_LO1 * v[15] + F_LO2 * v[16] + F_LO3 * v[17],
            F_LO0 * v[16] + F_LO1 * v[17] + F_LO2 * v[18] + F_LO3 * v[19]);
        *(float4*)(dst + 3120) = make_float4(
            F_HI0 * v[2] + F_HI1 * v[3] + F_HI2 * v[4] + F_HI3 * v[5],
            F_HI0 * v[4] + F_HI1 * v[5] + F_HI2 * v[6] + F_HI3 * v[7],
            F_HI0 * v[6] + F_HI1 * v[7] + F_HI2 * v[8] + F_HI3 * v[9],
            F_HI0 * v[8] + F_HI1 * v[9] + F_HI2 * v[10] + F_HI3 * v[11]);
        *(float4*)(dst + 3124) = make_float4(
            F_HI0 * v[10] + F_HI1 * v[11] + F_HI2 * v[12] + F_HI3 * v[13],
            F_HI0 * v[12] + F_HI1 * v[13] + F_HI2 * v[14] + F_HI3 * v[15],
            F_HI0 * v[14] + F_HI1 * v[15] + F_HI2 * v[16] + F_HI3 * v[17],
            F_HI0 * v[16] + F_HI1 * v[17] + F_HI2 * v[18] + F_HI3 * v[19]);
    }
    __syncthreads();

    // ---- v1 (R10 verbatim): 38 rows x 10 groups -> sA L1 bands (stride 40) ----
    if (tid < 380) {
        int r1 = tid / 10, k = tid - (tid / 10) * 10;
        const float* blo = sB + (2 * r1) * 40 + 4 * k;
        const float* bhi = blo + 3120;
        float4 L0 = *(const float4*)(blo);
        float4 L1v = *(const float4*)(blo + 40);
        float4 L2v = *(const float4*)(blo + 80);
        float4 L3v = *(const float4*)(blo + 120);
        float4 H0 = *(const float4*)(bhi);
        float4 H1 = *(const float4*)(bhi + 40);
        float4 H2 = *(const float4*)(bhi + 80);
        float4 H3 = *(const float4*)(bhi + 120);
        float4 b0 = vfilt(L0, L1v, L2v, L3v, F_LO0, F_LO1, F_LO2, F_LO3);
        float4 b1 = vfilt(L0, L1v, L2v, L3v, F_HI0, F_HI1, F_HI2, F_HI3);
        float4 b2 = vfilt(H0, H1, H2, H3, F_LO0, F_LO1, F_LO2, F_LO3);
        float4 b3 = vfilt(H0, H1, H2, H3, F_HI0, F_HI1, F_HI2, F_HI3);
        int wo = r1 * 40 + 4 * k;
        *(float4*)(sA + wo) = b0;
        *(float4*)(sA + 1520 + wo) = b1;
        *(float4*)(sA + 3040 + wo) = b2;
        *(float4*)(sA + 4560 + wo) = b3;
    }
    __syncthreads();
    if (edge) {  // patch reflected L1 slots (sources are fixed points: no race)
#pragma unroll
        for (int it = 0; it < 3; ++it) {
            int e = it * 512 + tid;
            if (e < 1444) {
                int lr = e / 38, lc = e - lr * 38;
                int sr = reflect_idx(O1r + lr, N1) - O1r;
                int sc = reflect_idx(O1c + lc, N1) - O1c;
                if ((sr != lr || sc != lc) && (unsigned)sr < 38u && (unsigned)sc < 38u) {
                    int da = lr * 40 + lc;
                    int sa = sr * 40 + sc;
                    sA[da] = sA[sa];
                    sA[1520 + da] = sA[1520 + sa];
                    sA[3040 + da] = sA[3040 + sa];
                    sA[4560 + da] = sA[4560 + sa];
                }
            }
        }
        __syncthreads();
    }

    // ---- L2 (NEW): 324 threads, one (r2,c2) cell; 16 loads shared across the
    //      4 outputs of each band; write slot == tid. sB := [16][324]. ----
    if (tid < 324) {
        const int r2 = tid / 18, c2 = tid - 18 * r2;
        const int rb = r2 * 80 + 2 * c2;
#pragma unroll
        for (int b = 0; b < 4; ++b) {
            const float* base = sA + b * 1520 + rb;
            float lo[4], hi[4];
#pragma unroll
            for (int u = 0; u < 4; ++u) {
                float2 a = *(const float2*)(base + u * 40);
                float2 d = *(const float2*)(base + u * 40 + 2);
                lo[u] = F_LO0 * a.x + F_LO1 * a.y + F_LO2 * d.x + F_LO3 * d.y;
                hi[u] = F_HI0 * a.x + F_HI1 * a.y + F_HI2 * d.x + F_HI3 * d.y;
            }
            float* dst = sB + (b * 4) * 324 + tid;
            dst[0]       = F_LO0 * lo[0] + F_LO1 * lo[1] + F_LO2 * lo[2] + F_LO3 * lo[3];
            dst[324]     = F_HI0 * lo[0] + F_HI1 * lo[1] + F_HI2 * lo[2] + F_HI3 * lo[3];
            dst[648]     = F_LO0 * hi[0] + F_LO1 * hi[1] + F_LO2 * hi[2] + F_LO3 * hi[3];
            dst[972]     = F_HI0 * hi[0] + F_HI1 * hi[1] + F_HI2 * hi[2] + F_HI3 * hi[3];
        }
    }
    __syncthreads();
    if (edge) {  // patch reflected L2 slots (full 18x18 tile; sources interior)
        if (tid < 324) {
            const int lr = tid / 18, lc = tid - 18 * lr;
            int sr = reflect_idx(O2r + lr, N2) - O2r;
            int sc = reflect_idx(O2c + lc, N2) - O2c;
            if ((sr != lr || sc != lc) && (unsigned)sr < 18u && (unsigned)sc < 18u) {
                int d = lr * 18 + lc;
                int s = sr * 18 + sc;
#pragma unroll
                for (int pl = 0; pl < 16; ++pl) sB[pl * 324 + d] = sB[pl * 324 + s];
            }
        }
        __syncthreads();
    }

    // ---- L3 (NEW): 512 threads x 2 items; all indices shifts/masks ----
    float local = 0.f;
    {
        const int pos = tid & 63;
        const int i = pos >> 3, j = pos & 7;
        const bool valid = (TA + i < N3) && (TB + j < N3);
        const int cell = (2 * i) * 18 + 2 * j;
#pragma unroll
        for (int q = 0; q < 2; ++q) {
            const int pl = (tid >> 6) + 8 * q;  // wave-uniform plane
            const float* pb = sB + pl * 324 + cell;
            float lo[4], hi[4];
#pragma unroll
            for (int u = 0; u < 4; ++u) {
                float2 a = *(const float2*)(pb + u * 18);
                float2 d = *(const float2*)(pb + u * 18 + 2);
                lo[u] = F_LO0 * a.x + F_LO1 * a.y + F_LO2 * d.x + F_LO3 * d.y;
                hi[u] = F_HI0 * a.x + F_HI1 * a.y + F_HI2 * d.x + F_HI3 * d.y;
            }
            float o0 = F_LO0 * lo[0] + F_LO1 * lo[1] + F_LO2 * lo[2] + F_LO3 * lo[3];
            float o1 = F_HI0 * lo[0] + F_HI1 * lo[1] + F_HI2 * lo[2] + F_HI3 * lo[3];
            float o2 = F_LO0 * hi[0] + F_LO1 * hi[1] + F_LO2 * hi[2] + F_LO3 * hi[3];
            float o3 = F_HI0 * hi[0] + F_HI1 * hi[1] + F_HI2 * hi[2] + F_HI3 * hi[3];
            if (valid) {
                float w00 = (pl == 0) ? 0.5f : 1.0f;
                local += w00 * o0 * o0 + o1 * o1 + o2 * o2 + o3 * o3;
            }
        }
    }

    // block reduction: 8 waves, one plain store per block (no atomic)
#pragma unroll
    for (int o = 32; o > 0; o >>= 1) local += __shfl_down(local, o, 64);
    const int w = tid >> 6;
    if ((tid & 63) == 0) wsum[w] = local;
    __syncthreads();
    if (tid == 0) {
        float ssum = 0.f;
#pragma unroll
        for (int x = 0; x < 8; ++x) ssum += wsum[x];
        partial[blockIdx.x] = ssum;
    }
}

// Final reduction: sum 15552 per-block partials -> out[0]. Single block.
__global__ void __launch_bounds__(1024) k_reduce(const float* __restrict__ part,
                                                 float* __restrict__ out,
                                                 int n4, float inv_den) {
    const int tid = threadIdx.x;
    float s = 0.f;
    const float4* p4 = (const float4*)part;
    for (int i = tid; i < n4; i += 1024) {
        float4 v = p4[i];
        s += v.x + v.y + v.z + v.w;
    }
#pragma unroll
    for (int o = 32; o > 0; o >>= 1) s += __shfl_down(s, o, 64);
    __shared__ float ws_[16];
    int w = tid >> 6;
    if ((tid & 63) == 0) ws_[w] = s;
    __syncthreads();
    if (tid == 0) {
        float tot = 0.f;
#pragma unroll
        for (int i = 0; i < 16; ++i) tot += ws_[i];
        out[0] = tot * inv_den;
    }
}

extern "C" void kernel_launch(void* const* d_in, const int* in_sizes, int n_in,
                              void* d_out, int out_size, void* d_ws, size_t ws_size,
                              hipStream_t stream) {
    const float* preds = (const float*)d_in[0];
    const float* targets = (const float*)d_in[1];
    float* out = (float*)d_out;
    float* partial = (float*)d_ws;  // 15552 floats = 62 KB

    const float inv_den = 1.0f / (192.0f * 66.0f * 66.0f);
    const int nblk = 192 * 9 * 9;  // 15552, divisible by 8

    k_wpt_fused<<<dim3(nblk), dim3(512), 0, stream>>>(preds, targets, partial);
    k_reduce<<<dim3(1), dim3(1024), 0, stream>>>(partial, out, nblk / 4, inv_den);
}